// Round 1
// 416.137 us; speedup vs baseline: 1.0934x; 1.0934x over previous
//
#include <hip/hip_runtime.h>

// CubeSpherePadding2D, p=1.  Input [16,64,6,96,96] f32 -> output [16,64,6,98,98].
// Round 3: single fused OUTPUT-INDEXED kernel.
//   - every thread writes one 16B-aligned float4 of the padded output
//     (OUT_FACE=9604 is divisible by 4, so tid*4 is always 16B aligned)
//   - reads are the scattered side; they are absorbed by the write-through L1
//     (stores cannot be -- CDNA L1 is no-write-allocate, which is why the old
//     input-indexed kernel's 4x scalar stores amplified L2 write requests 4x)
//   - edge/corner gather logic fused in (same verified tables as round 2)

#define BC_TOTAL 1024
#define NF 6
#define HH 96
#define HP 98
#define IN_FACE (HH * HH)     // 9216
#define OUT_FACE (HP * HP)    // 9604
#define NFACES (BC_TOTAL * NF)                 // 6144
#define NOUT4 (NFACES * OUT_FACE / 4)          // 14,751,744 float4 groups
// NOUT4 / 256 = 57,624 blocks exactly

// edge_tab[f*4 + edge] = {sf, br, kr, bc, kc}
// edge: 0=top(R==0), 1=bottom(R==97), 2=left(C==0), 3=right(C==97)
// t = C-1 for top/bottom, R-1 for left/right; src = I[sf][br+kr*t][bc+kc*t]
__constant__ short edge_tab[24][5] = {
    {4, 95, 0, 0, 1},  {5, 0, 0, 0, 1},   {3, 0, 1, 95, 0},  {1, 0, 1, 0, 0},
    {4, 95, -1, 95, 0},{5, 0, 1, 95, 0},  {0, 0, 1, 95, 0},  {2, 0, 1, 0, 0},
    {4, 0, 0, 95, -1}, {5, 95, 0, 95, -1},{1, 0, 1, 95, 0},  {3, 0, 1, 0, 0},
    {4, 0, 1, 0, 0},   {5, 95, -1, 0, 0}, {2, 0, 1, 95, 0},  {0, 0, 1, 0, 0},
    {2, 0, 0, 95, -1}, {0, 0, 0, 0, 1},   {3, 0, 0, 0, 1},   {1, 0, 0, 95, -1},
    {0, 95, 0, 0, 1},  {2, 95, 0, 95, -1},{3, 95, 0, 95, -1},{1, 95, 0, 0, 1},
};

// corner_tab[(f-4)*4 + cid] = {sf, sr, sc}; cid = (R==97)*2 + (C==97)
__constant__ short corner_tab[8][3] = {
    {3, 0, 0},  {1, 0, 95},  {3, 0, 95},  {1, 0, 0},
    {3, 95, 95},{1, 95, 0},  {3, 95, 0},  {1, 95, 95},
};

__device__ __forceinline__ float cube_val(const float* __restrict__ bcin,
                                          unsigned f, unsigned R, unsigned C) {
    unsigned r = R - 1u;   // wraps to huge for R==0
    unsigned c = C - 1u;
    bool rIn = r < (unsigned)HH;
    bool cIn = c < (unsigned)HH;

    if (rIn & cIn) {
        // interior -- the overwhelmingly common path
        return bcin[f * IN_FACE + r * HH + c];
    }
    if (rIn ^ cIn) {
        // edge (non-corner)
        int edge, t;
        if (!rIn) { edge = (R == 0u) ? 0 : 1; t = (int)c; }
        else      { edge = (C == 0u) ? 2 : 3; t = (int)r; }
        const short* ed = edge_tab[f * 4 + edge];
        int sr = (int)ed[1] + (int)ed[2] * t;
        int sc = (int)ed[3] + (int)ed[4] * t;
        return bcin[(unsigned)ed[0] * IN_FACE + (unsigned)sr * HH + (unsigned)sc];
    }
    // corner (both out of range)
    if (f < 4u) return 0.0f;
    int cid = ((R == 97u) ? 2 : 0) + ((C == 97u) ? 1 : 0);
    const short* ed = corner_tab[(f - 4u) * 4 + cid];
    return bcin[(unsigned)ed[0] * IN_FACE + (unsigned)ed[1] * HH + (unsigned)ed[2]];
}

__global__ __launch_bounds__(256) void pad_kernel(
    const float* __restrict__ in, float* __restrict__ out) {
    unsigned i4 = blockIdx.x * 256u + threadIdx.x;   // < NOUT4 exactly
    unsigned obase = i4 * 4u;                        // 16B-aligned output offset

    unsigned t2 = obase / OUT_FACE;                  // face linear id (bc*6+f)
    unsigned o  = obase - t2 * OUT_FACE;             // 0..9600, multiple of 4
    unsigned f  = t2 % NF;
    const float* bcin = in + (size_t)(t2 - f) * IN_FACE;   // face 0 of this bc

    unsigned R0 = o / HP;          // one division; elems walk from here
    unsigned C0 = o - R0 * HP;

    float vv[4];
    #pragma unroll
    for (int j = 0; j < 4; ++j) {
        unsigned C = C0 + (unsigned)j;
        unsigned R = R0;
        if (C >= (unsigned)HP) { C -= (unsigned)HP; R += 1u; }  // row crossing
        vv[j] = cube_val(bcin, f, R, C);
    }

    float4 v;
    v.x = vv[0]; v.y = vv[1]; v.z = vv[2]; v.w = vv[3];
    *(float4*)(out + obase) = v;                     // coalesced dwordx4 store
}

extern "C" void kernel_launch(void* const* d_in, const int* in_sizes, int n_in,
                              void* d_out, int out_size, void* d_ws, size_t ws_size,
                              hipStream_t stream) {
    const float* in = (const float*)d_in[0];
    float* out = (float*)d_out;

    hipLaunchKernelGGL(pad_kernel, dim3(NOUT4 / 256), dim3(256), 0, stream,
                       in, out);
}